// Round 3
// baseline (152.036 us; speedup 1.0000x reference)
//
#include <hip/hip_runtime.h>

// SupConLoss, B=8192, D=128, T=5.0 — round 3 (round-2 algebra, compile fix).
//   m'_i = s_ii = ||f_i||^2 / T  (fixed shift; loss shift-invariant, eps negligible)
//   Z_i  = sum_{j!=i} exp(s_ij - s_ii)          <- bf16 MFMA flash pass, 3 VALU/elem
//   A_i  = (f_i . g_{l_i} - ||f_i||^2)/T,  g_c = class sum (100 classes)
//   cnt_i = count[l_i] - 1
//   term_i = (A_i - cnt*s_ii)/cnt - log(1e-12+Z_i);  loss = -mean(term_i | cnt>0)
// 2 kernels + 1 memset; finalize folded into main via ticket atomics.

#define BN 8192
#define DK 128
#define NCLS 128              // labels < 100, padded
#define INV_T 0.2f
#define LOG2E 1.4426950408889634f

#define GX 32                 // row blocks, 256 rows each
#define GY 16                 // col chunks
#define CHUNK_COLS (BN / GY)  // 512

typedef __attribute__((ext_vector_type(8))) short bf16x8;   // 8 bf16 = 4 VGPRs
typedef __attribute__((ext_vector_type(4))) float f32x4;

// ---- ws layout (bytes) ----
#define OFF_FB   0                          // bf16 features, BN*DK*2 = 2 MB
#define OFF_SII  (BN * DK * 2)              // float[BN]
#define OFF_ZERO (OFF_SII + BN * 4)         // memset-zeroed region:
#define OFF_G    OFF_ZERO                   //   float[NCLS*DK]
#define OFF_CNT  (OFF_G + NCLS * DK * 4)    //   int[128]
#define OFF_Z    (OFF_CNT + 512)            //   float[BN]
#define OFF_RA   (OFF_Z + BN * 4)           //   float[BN]
#define OFF_TKT  (OFF_RA + BN * 4)          //   int[GX]
#define OFF_MISC (OFF_TKT + GX * 4)         //   int gTicket; float lossAcc
#define ZERO_BYTES (OFF_MISC + 128 - OFF_ZERO)

__device__ __forceinline__ unsigned short f2bf(float f) {
    unsigned u = __builtin_bit_cast(unsigned, f);
    u += 0x7fffu + ((u >> 16) & 1u);
    return (unsigned short)(u >> 16);
}

// prep: cast F->bf16, per-row s_ii, class sums g, class counts.
__global__ __launch_bounds__(256) void supcon_prep(const float* __restrict__ F,
                                                   const int* __restrict__ labels,
                                                   unsigned short* __restrict__ Fb,
                                                   float* __restrict__ sii,
                                                   float* __restrict__ g,
                                                   int* __restrict__ counts) {
    const int idx = blockIdx.x * 256 + threadIdx.x;   // float4 index, < BN*DK/4
    const int row = idx >> 5;                         // 32 float4 per row
    const int d0  = (idx & 31) * 4;
    float4 v = ((const float4*)F)[idx];

    ushort4 o;
    o.x = f2bf(v.x); o.y = f2bf(v.y); o.z = f2bf(v.z); o.w = f2bf(v.w);
    ((ushort4*)Fb)[idx] = o;

    const int lbl = labels[row];
    unsafeAtomicAdd(&g[lbl * DK + d0 + 0], v.x);
    unsafeAtomicAdd(&g[lbl * DK + d0 + 1], v.y);
    unsafeAtomicAdd(&g[lbl * DK + d0 + 2], v.z);
    unsafeAtomicAdd(&g[lbl * DK + d0 + 3], v.w);

    float sq = v.x * v.x + v.y * v.y + v.z * v.z + v.w * v.w;
    sq += __shfl_xor(sq, 1);  sq += __shfl_xor(sq, 2);  sq += __shfl_xor(sq, 4);
    sq += __shfl_xor(sq, 8);  sq += __shfl_xor(sq, 16);
    if ((threadIdx.x & 31) == 0) {
        sii[row] = sq * INV_T;
        atomicAdd(&counts[lbl], 1);
    }
}

__global__ __launch_bounds__(256) void supcon_main(
    const short* __restrict__ Fb, const float* __restrict__ F,
    const int* __restrict__ labels, const float* __restrict__ sii,
    const float* __restrict__ g, const int* __restrict__ counts,
    float* __restrict__ Zrow, float* __restrict__ rowA,
    int* __restrict__ rbTicket, int* __restrict__ gTicket,
    float* __restrict__ lossAcc, float* __restrict__ out)
{
    const int tid  = threadIdx.x;
    const int wave = tid >> 6, lane = tid & 63;
    const int quad = lane >> 4, l16 = lane & 15;
    const int bx = blockIdx.x, by = blockIdx.y;
    const int rowBase = bx * 256 + wave * 64;   // 4 waves * 64 rows (RT=4)
    const int colBase = by * CHUNK_COLS;

    __shared__ int   tkt;
    __shared__ float ss[4];

    // per-row A-term: only the y==0 chunk block for this row-block computes it
    if (by == 0) {
        const int r0  = bx * 256 + tid;
        const int lbl = labels[r0];
        const float c = (float)(counts[lbl] - 1);
        if (c > 0.5f) {
            const float4* fr = (const float4*)(F + (size_t)r0 * DK);
            const float4* gr = (const float4*)(g + (size_t)lbl * DK);
            float dot = 0.f;
#pragma unroll
            for (int d = 0; d < DK / 4; ++d) {
                float4 a = fr[d], b = gr[d];
                dot += a.x * b.x + a.y * b.y + a.z * b.z + a.w * b.w;
            }
            const float s2 = sii[r0];
            const float A  = dot * INV_T - s2;           // excludes self
            unsafeAtomicAdd(&rowA[r0], (A - c * s2) / c);
        }
    }

    // A fragments: rows rowBase..rowBase+63 (verified 16x16x32 layout)
    bf16x8 a[4][4];
#pragma unroll
    for (int rt = 0; rt < 4; ++rt)
#pragma unroll
        for (int kt = 0; kt < 4; ++kt)
            a[rt][kt] = *(const bf16x8*)(Fb + (size_t)(rowBase + rt * 16 + l16) * DK
                                            + kt * 32 + quad * 8);

    // per-lane row shifts: row = rowBase + rt*16 + quad*4 + r  (C/D layout)
    float nc2[4][4];
#pragma unroll
    for (int rt = 0; rt < 4; ++rt)
#pragma unroll
        for (int r = 0; r < 4; ++r)
            nc2[rt][r] = -sii[rowBase + rt * 16 + quad * 4 + r] * LOG2E;

    float Z[4][4];
#pragma unroll
    for (int rt = 0; rt < 4; ++rt)
#pragma unroll
        for (int r = 0; r < 4; ++r) Z[rt][r] = 0.f;

    const float K2 = INV_T * LOG2E;

    for (int jt = 0; jt < CHUNK_COLS / 16; ++jt) {
        const int j0 = colBase + jt * 16;
        bf16x8 b[4];
#pragma unroll
        for (int kt = 0; kt < 4; ++kt)
            b[kt] = *(const bf16x8*)(Fb + (size_t)(j0 + l16) * DK + kt * 32 + quad * 8);

#pragma unroll
        for (int rt = 0; rt < 4; ++rt) {
            f32x4 acc = {0.f, 0.f, 0.f, 0.f};
#pragma unroll
            for (int kt = 0; kt < 4; ++kt)
                acc = __builtin_amdgcn_mfma_f32_16x16x32_bf16(a[rt][kt], b[kt], acc, 0, 0, 0);

            const bool dt = (j0 == rowBase + rt * 16);   // wave-uniform diag tile
#pragma unroll
            for (int r = 0; r < 4; ++r) {
                float e = __builtin_amdgcn_exp2f(fmaf(acc[r], K2, nc2[rt][r]));
                if (dt && (l16 == quad * 4 + r)) e = 0.f;
                Z[rt][r] += e;
            }
        }
    }

    // sum over the 16 columns each lane-group covers, accumulate per row
#pragma unroll
    for (int rt = 0; rt < 4; ++rt)
#pragma unroll
        for (int r = 0; r < 4; ++r) {
            float z = Z[rt][r];
            z += __shfl_xor(z, 1); z += __shfl_xor(z, 2);
            z += __shfl_xor(z, 4); z += __shfl_xor(z, 8);
            if (l16 == 0)
                unsafeAtomicAdd(&Zrow[rowBase + rt * 16 + quad * 4 + r], z);
        }

    // ticket: last of the GY chunk-blocks for this row-block finalizes its 256 rows
    __syncthreads();                     // drains this block's atomics (vmcnt(0))
    if (tid == 0) { __threadfence(); tkt = atomicAdd(&rbTicket[bx], 1); }
    __syncthreads();
    if (tkt == GY - 1) {
        const int i  = bx * 256 + tid;
        const float Zv = unsafeAtomicAdd(&Zrow[i], 0.f);   // coherent read
        const float Av = unsafeAtomicAdd(&rowA[i], 0.f);
        const int   c  = counts[labels[i]] - 1;
        float term = (c > 0) ? (Av - __logf(1e-12f + Zv)) : 0.f;
#pragma unroll
        for (int h = 1; h < 64; h <<= 1) term += __shfl_xor(term, h);
        if (lane == 0) ss[wave] = term;
        __syncthreads();
        if (tid == 0) {
            unsafeAtomicAdd(lossAcc, ss[0] + ss[1] + ss[2] + ss[3]);
            __threadfence();
            const int gt = atomicAdd(gTicket, 1);
            if (gt == GX - 1)
                out[0] = -unsafeAtomicAdd(lossAcc, 0.f) * (1.0f / BN);
        }
    }
}

extern "C" void kernel_launch(void* const* d_in, const int* in_sizes, int n_in,
                              void* d_out, int out_size, void* d_ws, size_t ws_size,
                              hipStream_t stream) {
    const float* F      = (const float*)d_in[0];
    const int*   labels = (const int*)d_in[1];
    float* out = (float*)d_out;
    char*  ws  = (char*)d_ws;

    unsigned short* Fb     = (unsigned short*)(ws + OFF_FB);
    float*          sii    = (float*)(ws + OFF_SII);
    float*          g      = (float*)(ws + OFF_G);
    int*            counts = (int*)(ws + OFF_CNT);
    float*          Zrow   = (float*)(ws + OFF_Z);
    float*          rowA   = (float*)(ws + OFF_RA);
    int*            rbTkt  = (int*)(ws + OFF_TKT);
    int*            gTkt   = (int*)(ws + OFF_MISC);
    float*          lossA  = (float*)(ws + OFF_MISC + 4);

    (void)hipMemsetAsync(ws + OFF_ZERO, 0, ZERO_BYTES, stream);
    supcon_prep<<<BN * DK / 4 / 256, 256, 0, stream>>>(F, labels, Fb, sii, g, counts);
    supcon_main<<<dim3(GX, GY), 256, 0, stream>>>((const short*)Fb, F, labels, sii,
                                                  g, counts, Zrow, rowA,
                                                  rbTkt, gTkt, lossA, out);
}